// Round 1
// baseline (445.951 us; speedup 1.0000x reference)
//
#include <hip/hip_runtime.h>
#include <hip/hip_bf16.h>

#define HW_   (512 * 512)
#define B_    4
#define D_    64
#define NPIX  (B_ * HW_)          // 1048576
#define NW    19                  // within channels used (20 - 1)
#define NC    26                  // cross channels used  (27 - 1)
#define NLAB  (NW + NC)           // 45
#define NSEG  20                  // centroid segments
#define THREADS 256
#define TILE  (THREADS * 2)       // 512 pixels per block (divides HW_)

template<int P>
__device__ __forceinline__ float comp(float2 v) { return (P == 0) ? v.x : v.y; }

// entropy of softmax over acc[LO .. LO+NCH-1] (component P of the float2)
template<int LO, int NCH, int P>
__device__ __forceinline__ float entropy_of(const float2* acc) {
    float m = comp<P>(acc[LO]);
#pragma unroll
    for (int i = 1; i < NCH; ++i) m = fmaxf(m, comp<P>(acc[LO + i]));
    float S = 0.f, W = 0.f;
#pragma unroll
    for (int i = 0; i < NCH; ++i) {
        float s = comp<P>(acc[LO + i]) - m;
        float e = __expf(s);
        S += e;
        W = fmaf(e, s, W);
    }
    return __logf(S) - W / S;
}

__global__ __launch_bounds__(THREADS, 3)
void fused_embed(const float* __restrict__ enc, const float* __restrict__ wW,
                 const float* __restrict__ wC, const int* __restrict__ targ,
                 float* __restrict__ out)
{
    __shared__ float sW[NLAB][D_];        // 11.25 KB weights (within rows 0..18, cross 19..44)
    __shared__ float sCent[NSEG][D_ + 1]; // +1 pad -> labels hit distinct banks
    __shared__ int   sCount[NSEG];
    __shared__ float sRed[THREADS / 64];

    const int tid = threadIdx.x;

    for (int i = tid; i < NLAB * D_; i += THREADS) {
        int n = i >> 6, d = i & 63;
        sW[n][d] = (n < NW) ? wW[n * D_ + d] : wC[(n - NW) * D_ + d];
    }
    for (int i = tid; i < NSEG * (D_ + 1); i += THREADS) (&sCent[0][0])[i] = 0.f;
    if (tid < NSEG) sCount[tid] = 0;
    __syncthreads();

    const int p0  = blockIdx.x * TILE + tid * 2;   // this thread's pixel pair
    const int b   = (blockIdx.x * TILE) / HW_;     // whole block inside one batch image
    const int hw0 = p0 - b * HW_;
    const float* fp = enc + (size_t)b * (D_ * HW_) + hw0;
    const int lab0 = targ[p0];
    const int lab1 = targ[p0 + 1];

    float2 acc[NLAB];
#pragma unroll
    for (int n = 0; n < NLAB; ++n) acc[n] = make_float2(0.f, 0.f);

#pragma unroll 1
    for (int dc = 0; dc < D_ / 4; ++dc) {
        const float* fpc = fp + (size_t)dc * 4 * HW_;
        float2 f0 = *(const float2*)(fpc);
        float2 f1 = *(const float2*)(fpc + HW_);
        float2 f2 = *(const float2*)(fpc + 2 * HW_);
        float2 f3 = *(const float2*)(fpc + 3 * HW_);

        // centroid accumulation (LDS atomics, no-return -> ds_add_f32)
        atomicAdd(&sCent[lab0][dc * 4 + 0], f0.x);
        atomicAdd(&sCent[lab1][dc * 4 + 0], f0.y);
        atomicAdd(&sCent[lab0][dc * 4 + 1], f1.x);
        atomicAdd(&sCent[lab1][dc * 4 + 1], f1.y);
        atomicAdd(&sCent[lab0][dc * 4 + 2], f2.x);
        atomicAdd(&sCent[lab1][dc * 4 + 2], f2.y);
        atomicAdd(&sCent[lab0][dc * 4 + 3], f3.x);
        atomicAdd(&sCent[lab1][dc * 4 + 3], f3.y);

#pragma unroll
        for (int n = 0; n < NLAB; ++n) {
            float4 w4 = *(const float4*)&sW[n][dc * 4];   // wave-uniform broadcast
            float ax = acc[n].x, ay = acc[n].y;
            ax = fmaf(w4.x, f0.x, ax);  ay = fmaf(w4.x, f0.y, ay);
            ax = fmaf(w4.y, f1.x, ax);  ay = fmaf(w4.y, f1.y, ay);
            ax = fmaf(w4.z, f2.x, ax);  ay = fmaf(w4.z, f2.y, ay);
            ax = fmaf(w4.w, f3.x, ax);  ay = fmaf(w4.w, f3.y, ay);
            acc[n].x = ax; acc[n].y = ay;
        }
    }

    atomicAdd(&sCount[lab0], 1);
    atomicAdd(&sCount[lab1], 1);

    // per-pixel entropies: within = rows [0,19), cross = rows [19,45)  (T=1, alpha=beta=0.5)
    float lossAcc = entropy_of<0, NW, 0>(acc) + entropy_of<NW, NC, 0>(acc)
                  + entropy_of<0, NW, 1>(acc) + entropy_of<NW, NC, 1>(acc);

    // wave reduce (64 lanes)
#pragma unroll
    for (int off = 32; off; off >>= 1) lossAcc += __shfl_down(lossAcc, off);
    if ((tid & 63) == 0) sRed[tid >> 6] = lossAcc;
    __syncthreads();
    if (tid == 0) {
        float s = 0.f;
#pragma unroll
        for (int w = 0; w < THREADS / 64; ++w) s += sRed[w];
        atomicAdd(out, s * (0.5f / (float)NPIX));
    }

    // flush centroids + counts (counts written as float: harness reads buffer as f32)
    for (int i = tid; i < NSEG * D_; i += THREADS) {
        int n = i >> 6, d = i & 63;
        atomicAdd(&out[1 + i], sCent[n][d]);
    }
    if (tid < NSEG) atomicAdd(&out[1 + NSEG * D_ + tid], (float)sCount[tid]);
}

extern "C" void kernel_launch(void* const* d_in, const int* in_sizes, int n_in,
                              void* d_out, int out_size, void* d_ws, size_t ws_size,
                              hipStream_t stream) {
    const float* enc = (const float*)d_in[0];
    const float* wW  = (const float*)d_in[1];
    const float* wC  = (const float*)d_in[2];
    const int*   targ = (const int*)d_in[3];
    float* out = (float*)d_out;

    // d_out is poisoned 0xAA once before timing and never re-poisoned; we accumulate
    // with atomics, so zero it ourselves every call (memset node is graph-capturable).
    hipMemsetAsync(d_out, 0, (size_t)out_size * sizeof(float), stream);

    fused_embed<<<dim3(NPIX / TILE), dim3(THREADS), 0, stream>>>(enc, wW, wC, targ, out);
}

// Round 2
// 360.103 us; speedup vs baseline: 1.2384x; 1.2384x over previous
//
#include <hip/hip_runtime.h>
#include <hip/hip_bf16.h>

#define HW_   (512 * 512)
#define B_    4
#define D_    64
#define NPIX  (B_ * HW_)          // 1048576
#define NW    19                  // within channels used (20 - 1)
#define NC    26                  // cross channels used  (27 - 1)
#define NLAB  (NW + NC)           // 45
#define NSEG  20                  // centroid segments
#define THREADS 256
#define TILE  (THREADS * 2)       // 512 pixels per block (divides HW_)

__global__ __launch_bounds__(THREADS, 3)
void fused_embed(const float* __restrict__ enc, const float* __restrict__ wW,
                 const float* __restrict__ wC, const int* __restrict__ targ,
                 float* __restrict__ out)
{
    __shared__ float sCent[NSEG][D_ + 1]; // +1 pad -> labels hit distinct banks
    __shared__ int   sCount[NSEG];
    __shared__ float sRed[THREADS / 64];

    const int tid = threadIdx.x;

    for (int i = tid; i < NSEG * (D_ + 1); i += THREADS) (&sCent[0][0])[i] = 0.f;
    if (tid < NSEG) sCount[tid] = 0;
    __syncthreads();

    const int p0  = blockIdx.x * TILE + tid * 2;   // this thread's pixel pair
    const int b   = (blockIdx.x * TILE) / HW_;     // whole block inside one batch image
    const int hw0 = p0 - b * HW_;
    const float* fp = enc + (size_t)b * (D_ * HW_) + hw0;
    const int lab0 = targ[p0];
    const int lab1 = targ[p0 + 1];

    // accumulators: stay strictly in VGPRs (no address ever taken, all indices
    // compile-time after full unroll)
    float accx[NLAB], accy[NLAB];
#pragma unroll
    for (int n = 0; n < NLAB; ++n) { accx[n] = 0.f; accy[n] = 0.f; }

#pragma unroll 2
    for (int dc = 0; dc < D_ / 4; ++dc) {
        const float* fpc = fp + (size_t)dc * 4 * HW_;
        float2 f0 = *(const float2*)(fpc);
        float2 f1 = *(const float2*)(fpc + HW_);
        float2 f2 = *(const float2*)(fpc + 2 * HW_);
        float2 f3 = *(const float2*)(fpc + 3 * HW_);

        // centroid accumulation (LDS atomics -> ds_add_f32; LDS pipe is
        // otherwise idle now that weights come via the scalar pipe)
        atomicAdd(&sCent[lab0][dc * 4 + 0], f0.x);
        atomicAdd(&sCent[lab1][dc * 4 + 0], f0.y);
        atomicAdd(&sCent[lab0][dc * 4 + 1], f1.x);
        atomicAdd(&sCent[lab1][dc * 4 + 1], f1.y);
        atomicAdd(&sCent[lab0][dc * 4 + 2], f2.x);
        atomicAdd(&sCent[lab1][dc * 4 + 2], f2.y);
        atomicAdd(&sCent[lab0][dc * 4 + 3], f3.x);
        atomicAdd(&sCent[lab1][dc * 4 + 3], f3.y);

#pragma unroll
        for (int n = 0; n < NLAB; ++n) {
            // wave-uniform, compile-time-indexed, readonly -> s_load_dwordx4
            const float* wrow = (n < NW) ? (wW + n * D_) : (wC + (n - NW) * D_);
            float4 w4 = *(const float4*)(wrow + dc * 4);
            float ax = accx[n], ay = accy[n];
            ax = fmaf(w4.x, f0.x, ax);  ay = fmaf(w4.x, f0.y, ay);
            ax = fmaf(w4.y, f1.x, ax);  ay = fmaf(w4.y, f1.y, ay);
            ax = fmaf(w4.z, f2.x, ax);  ay = fmaf(w4.z, f2.y, ay);
            ax = fmaf(w4.w, f3.x, ax);  ay = fmaf(w4.w, f3.y, ay);
            accx[n] = ax; accy[n] = ay;
        }
    }

    atomicAdd(&sCount[lab0], 1);
    atomicAdd(&sCount[lab1], 1);

    // ---- entropies, fully inline (no pointer to acc escapes) ----
    float lossAcc = 0.f;
    {   // within: rows [0, NW)
        float m0 = accx[0], m1 = accy[0];
#pragma unroll
        for (int i = 1; i < NW; ++i) { m0 = fmaxf(m0, accx[i]); m1 = fmaxf(m1, accy[i]); }
        float S0 = 0.f, W0 = 0.f, S1 = 0.f, W1 = 0.f;
#pragma unroll
        for (int i = 0; i < NW; ++i) {
            float s0 = accx[i] - m0, e0 = __expf(s0); S0 += e0; W0 = fmaf(e0, s0, W0);
            float s1 = accy[i] - m1, e1 = __expf(s1); S1 += e1; W1 = fmaf(e1, s1, W1);
        }
        lossAcc += (__logf(S0) - W0 / S0) + (__logf(S1) - W1 / S1);
    }
    {   // cross: rows [NW, NW+NC)
        float m0 = accx[NW], m1 = accy[NW];
#pragma unroll
        for (int i = NW + 1; i < NLAB; ++i) { m0 = fmaxf(m0, accx[i]); m1 = fmaxf(m1, accy[i]); }
        float S0 = 0.f, W0 = 0.f, S1 = 0.f, W1 = 0.f;
#pragma unroll
        for (int i = NW; i < NLAB; ++i) {
            float s0 = accx[i] - m0, e0 = __expf(s0); S0 += e0; W0 = fmaf(e0, s0, W0);
            float s1 = accy[i] - m1, e1 = __expf(s1); S1 += e1; W1 = fmaf(e1, s1, W1);
        }
        lossAcc += (__logf(S0) - W0 / S0) + (__logf(S1) - W1 / S1);
    }

    // wave reduce (64 lanes)
#pragma unroll
    for (int off = 32; off; off >>= 1) lossAcc += __shfl_down(lossAcc, off);
    if ((tid & 63) == 0) sRed[tid >> 6] = lossAcc;
    __syncthreads();
    if (tid == 0) {
        float s = 0.f;
#pragma unroll
        for (int w = 0; w < THREADS / 64; ++w) s += sRed[w];
        atomicAdd(out, s * (0.5f / (float)NPIX));
    }

    // flush centroids + counts (counts written as float: harness reads buffer as f32)
    for (int i = tid; i < NSEG * D_; i += THREADS) {
        int n = i >> 6, d = i & 63;
        atomicAdd(&out[1 + i], sCent[n][d]);
    }
    if (tid < NSEG) atomicAdd(&out[1 + NSEG * D_ + tid], (float)sCount[tid]);
}

extern "C" void kernel_launch(void* const* d_in, const int* in_sizes, int n_in,
                              void* d_out, int out_size, void* d_ws, size_t ws_size,
                              hipStream_t stream) {
    const float* enc = (const float*)d_in[0];
    const float* wW  = (const float*)d_in[1];
    const float* wC  = (const float*)d_in[2];
    const int*   targ = (const int*)d_in[3];
    float* out = (float*)d_out;

    // d_out is poisoned 0xAA once before timing and never re-poisoned; we accumulate
    // with atomics, so zero it ourselves every call (memset node is graph-capturable).
    hipMemsetAsync(d_out, 0, (size_t)out_size * sizeof(float), stream);

    fused_embed<<<dim3(NPIX / TILE), dim3(THREADS), 0, stream>>>(enc, wW, wC, targ, out);
}